// Round 10
// baseline (486.174 us; speedup 1.0000x reference)
//
#include <hip/hip_runtime.h>
#include <hip/hip_bf16.h>
#include <stdint.h>

#define TOKENS 4096
#define IN_F   4096
#define OUT_F  16384
#define NT     (IN_F / 64)   // 64 K-tiles of BK=64 (i8)

#define QSCALE (6.0f / 127.0f)   // dequant scale
#define QINV   (127.0f / 6.0f)   // quant scale

using i32x4  = __attribute__((ext_vector_type(4))) int;

// ---- preprocessing: quantize x -> i8, ternarize w1,w2 -> i8 ------------------
__global__ __launch_bounds__(256) void k_xquant(const float4* __restrict__ x,
                                                int4* __restrict__ xb, int n16) {
    int idx = blockIdx.x * blockDim.x + threadIdx.x;
    int stride = gridDim.x * blockDim.x;
    for (int i = idx; i < n16; i += stride) {
        union { signed char c[16]; int4 v; } u;
#pragma unroll
        for (int j = 0; j < 4; ++j) {
            float4 a = x[i * 4 + j];
            float vals[4] = { a.x, a.y, a.z, a.w };
#pragma unroll
            for (int e = 0; e < 4; ++e) {
                int q = __float2int_rn(vals[e] * QINV);
                q = q > 127 ? 127 : (q < -127 ? -127 : q);
                u.c[j * 4 + e] = (signed char)q;
            }
        }
        xb[i] = u.v;
    }
}

__global__ __launch_bounds__(256) void k_ternarize(const float4* __restrict__ w1,
                                                   const float4* __restrict__ w2,
                                                   int4* __restrict__ wb, int n16) {
    int idx = blockIdx.x * blockDim.x + threadIdx.x;
    int stride = gridDim.x * blockDim.x;
    for (int i = idx; i < n16; i += stride) {
        union { signed char c[16]; int4 v; } u;
#pragma unroll
        for (int j = 0; j < 4; ++j) {
            float4 a = w1[i * 4 + j];
            float4 b = w2[i * 4 + j];
            float av[4] = { a.x, a.y, a.z, a.w };
            float bv[4] = { b.x, b.y, b.z, b.w };
#pragma unroll
            for (int e = 0; e < 4; ++e) {
                int s = ((av[e] > 0.f) - (av[e] < 0.f)) + ((bv[e] > 0.f) - (bv[e] < 0.f));
                u.c[j * 4 + e] = (signed char)(s / 2);   // {-1, 0, +1}
            }
        }
        wb[i] = u.v;
    }
}

// ---- helpers -----------------------------------------------------------------
#define GLDS(gp, lp) __builtin_amdgcn_global_load_lds(                          \
    (const __attribute__((address_space(1))) uint32_t*)(gp),                    \
    (__attribute__((address_space(3))) uint32_t*)(lp), 16, 0, 0)

// LDS XOR swizzle: flip byte bits [5:4] with row bits [2:1] (z bits [8:7]).
// Involution on 16B chunks; measured conflict-free for the 16-row ds_read_b128
// fragment pattern (rounds 2/3/5/6/9: SQ_LDS_BANK_CONFLICT == 0).
#define SWZ(z) ((z) ^ ((((z) >> 7) & 3) << 4))

#define WAITV(n) __asm__ __volatile__("s_waitcnt vmcnt(" #n ")")
#define WAITL0() __asm__ __volatile__("s_waitcnt lgkmcnt(0)")
#define BAR()    __builtin_amdgcn_s_barrier()
#define SCHED0() __builtin_amdgcn_sched_barrier(0)

// ---- main GEMM: 256x256 tile, BK=64 i8, 4 waves, per-wave 128x128 ------------
// C[M,N] = (A[M,K]i8 * B[N,K]i8^T) * QSCALE + bias, 16x16x64 i8 MFMA.
// 4 waves (2M x 2N), per-wave 16 frag reads -> 64 MFMA (LDS/MFMA 25% vs 37.5%
// in the 8-wave version). acc 8x8xi32x4 = 256 VGPR -> 1 wave/SIMD.
// Ring-4 x 32KB LDS, stage T+3 during T, steady-state vmcnt(16) (8 loads/tile).
__global__ __launch_bounds__(256, 1) void k_gemmi8(const signed char* __restrict__ A,
                                                   const signed char* __restrict__ B,
                                                   const float* __restrict__ bias,
                                                   float* __restrict__ C) {
    extern __shared__ __align__(16) char smem[];   // 4 bufs x (A 16KB + B 16KB) = 128KB

    const int tid  = threadIdx.x;
    const int lane = tid & 63;
    const int wave = tid >> 6;     // 0..3
    const int wm = wave >> 1;      // 0..1  (M half)
    const int wn = wave & 1;       // 0..1  (N half)
    const int lr = lane & 15;
    const int hk = lane >> 4;      // 0..3

    // XCD-aware swizzle: XCD x owns wgp in [x*128,(x+1)*128) (1024 % 8 == 0)
    const int bid = blockIdx.x;
    const int wgp = (bid & 7) * 128 + (bid >> 3);
    const int mBase = (wgp & 15) * 256;
    const int nBase = (wgp >> 4) * 256;

    // swizzled ds_read offsets (bytes within 16KB region; rows are 64B)
    int zA[8], zB[8];
#pragma unroll
    for (int i = 0; i < 8; ++i) {
        int za = (wm * 128 + i * 16 + lr) * 64 + hk * 16;
        int zb = (wn * 128 + i * 16 + lr) * 64 + hk * 16;
        zA[i] = SWZ(za);
        zB[i] = SWZ(zb);
    }

    // staging: linear LDS dest chunks (4 per region per thread); source
    // inverse-swizzled (rule #21)
    auto soff = [](int q) -> size_t {   // byte offset within a [256 rows][IN_F] i8 panel
        int z  = q * 16;
        int zs = SWZ(z);
        return (size_t)(zs >> 6) * IN_F + (size_t)(zs & 63);
    };
    const signed char* gA[4];
    const signed char* gB[4];
#pragma unroll
    for (int c = 0; c < 4; ++c) {
        gA[c] = A + (size_t)mBase * IN_F + soff(tid + 256 * c);
        gB[c] = B + (size_t)nBase * IN_F + soff(tid + 256 * c);
    }

    char* const bufs[4] = { smem, smem + 32768, smem + 65536, smem + 98304 };

#define STG_A(bb, tt) do {                                                      \
    _Pragma("unroll")                                                           \
    for (int c = 0; c < 4; ++c)                                                 \
        GLDS(gA[c] + (size_t)(tt) * 64, (bb) + tid * 16 + c * 4096);            \
} while (0)
#define STG_B(bb, tt) do {                                                      \
    _Pragma("unroll")                                                           \
    for (int c = 0; c < 4; ++c)                                                 \
        GLDS(gB[c] + (size_t)(tt) * 64, (bb) + 16384 + tid * 16 + c * 4096);    \
} while (0)

    i32x4 acc[8][8] = {};

    // prologue: stage tiles 0,1,2 (24 loads/thread in flight)
#pragma unroll
    for (int t = 0; t < 3; ++t) {
        STG_A(bufs[t], t);
        STG_B(bufs[t], t);
    }
    WAITV(16);       // tile 0 landed; tiles 1,2 still in flight
    BAR();
    SCHED0();

    // One K-tile: 2 fence-disciplined phases; counted vmcnt at tile end.
#define TILE(TT, POS, DOSTAGE, WN) do {                                         \
    char* bufA = bufs[(POS)];                                                   \
    char* bufB = bufA + 16384;                                                  \
    char* sb   = bufs[((POS) + 3) & 3];                                         \
    i32x4 a[8], b0[4], b1[4];                                                   \
    /* ---- phase 0: read a[8]+b0[4], stage next-A ---- */                      \
    _Pragma("unroll")                                                           \
    for (int i = 0; i < 8; ++i) a[i] = *(const i32x4*)(bufA + zA[i]);           \
    _Pragma("unroll")                                                           \
    for (int j = 0; j < 4; ++j) b0[j] = *(const i32x4*)(bufB + zB[j]);          \
    if (DOSTAGE) STG_A(sb, (TT) + 3);                                           \
    SCHED0();                                                                   \
    BAR();                                                                      \
    WAITL0();                                                                   \
    SCHED0();                                                                   \
    __builtin_amdgcn_s_setprio(1);                                              \
    _Pragma("unroll")                                                           \
    for (int i = 0; i < 8; ++i)                                                 \
        _Pragma("unroll")                                                       \
        for (int j = 0; j < 4; ++j)                                             \
            acc[i][j] = __builtin_amdgcn_mfma_i32_16x16x64_i8(a[i], b0[j],      \
                                                              acc[i][j], 0, 0, 0); \
    __builtin_amdgcn_s_setprio(0);                                              \
    SCHED0();                                                                   \
    BAR();                                                                      \
    /* ---- phase 1: read b1[4], stage next-B ---- */                           \
    _Pragma("unroll")                                                           \
    for (int j = 0; j < 4; ++j) b1[j] = *(const i32x4*)(bufB + zB[4 + j]);      \
    if (DOSTAGE) STG_B(sb, (TT) + 3);                                           \
    SCHED0();                                                                   \
    BAR();                                                                      \
    WAITL0();                                                                   \
    SCHED0();                                                                   \
    __builtin_amdgcn_s_setprio(1);                                              \
    _Pragma("unroll")                                                           \
    for (int i = 0; i < 8; ++i)                                                 \
        _Pragma("unroll")                                                       \
        for (int j = 0; j < 4; ++j)                                             \
            acc[i][4 + j] = __builtin_amdgcn_mfma_i32_16x16x64_i8(a[i], b1[j],  \
                                                                  acc[i][4 + j], 0, 0, 0); \
    __builtin_amdgcn_s_setprio(0);                                              \
    WN;                                                                         \
    SCHED0();                                                                   \
    BAR();                                                                      \
} while (0)

#pragma unroll 1
    for (int T0 = 0; T0 < NT - 4; T0 += 4) {   // tiles 0..59, always staging
        TILE(T0 + 0, 0, 1, WAITV(16));
        TILE(T0 + 1, 1, 1, WAITV(16));
        TILE(T0 + 2, 2, 1, WAITV(16));
        TILE(T0 + 3, 3, 1, WAITV(16));
    }
    // tail: tiles 60..63 — tile 60 stages 63; then drain 16 -> 8 -> 0
    TILE(NT - 4, 0, 1, WAITV(16));
    TILE(NT - 3, 1, 0, WAITV(8));
    TILE(NT - 2, 2, 0, WAITV(0));
    TILE(NT - 1, 3, 0, ((void)0));
#undef TILE
#undef STG_A
#undef STG_B

    // epilogue: C/D layout col = lane&15, row = (lane>>4)*4 + reg; dequant
#pragma unroll
    for (int i = 0; i < 8; ++i) {
        const int row = mBase + wm * 128 + i * 16 + hk * 4;
#pragma unroll
        for (int j = 0; j < 8; ++j) {
            const int col = nBase + wn * 128 + j * 16 + lr;
            const float bv = bias[col];
#pragma unroll
            for (int q = 0; q < 4; ++q)
                C[(size_t)(row + q) * OUT_F + col] = (float)acc[i][j][q] * QSCALE + bv;
        }
    }
}

// ---- fp32 fallback (ws too small or attribute failure) -----------------------
static __device__ __forceinline__ float tern(float a, float b) {
    float sa = (a > 0.f) ? 1.f : ((a < 0.f) ? -1.f : 0.f);
    float sb = (b > 0.f) ? 1.f : ((b < 0.f) ? -1.f : 0.f);
    return 0.5f * (sa + sb);
}

__global__ __launch_bounds__(256) void k_fallback(const float* __restrict__ x,
                                                  const float* __restrict__ w1,
                                                  const float* __restrict__ w2,
                                                  const float* __restrict__ bias,
                                                  float* __restrict__ C) {
    __shared__ float sx[64][17];
    __shared__ float sw[64][17];
    const int tid = threadIdx.x;
    const int mb = blockIdx.y * 64, nb = blockIdx.x * 64;
    const int ty = tid >> 4, tx = tid & 15;
    float acc[4][4] = {};
    const int r = tid >> 2, s = (tid & 3) * 4;
    for (int k0 = 0; k0 < IN_F; k0 += 16) {
        float4 xv = *(const float4*)&x[(size_t)(mb + r) * IN_F + k0 + s];
        float4 a1 = *(const float4*)&w1[(size_t)(nb + r) * IN_F + k0 + s];
        float4 a2 = *(const float4*)&w2[(size_t)(nb + r) * IN_F + k0 + s];
        sx[r][s + 0] = xv.x; sx[r][s + 1] = xv.y; sx[r][s + 2] = xv.z; sx[r][s + 3] = xv.w;
        sw[r][s + 0] = tern(a1.x, a2.x); sw[r][s + 1] = tern(a1.y, a2.y);
        sw[r][s + 2] = tern(a1.z, a2.z); sw[r][s + 3] = tern(a1.w, a2.w);
        __syncthreads();
#pragma unroll
        for (int kk = 0; kk < 16; ++kk) {
            float av[4], bv[4];
#pragma unroll
            for (int i = 0; i < 4; ++i) av[i] = sx[ty * 4 + i][kk];
#pragma unroll
            for (int j = 0; j < 4; ++j) bv[j] = sw[tx * 4 + j][kk];
#pragma unroll
            for (int i = 0; i < 4; ++i)
#pragma unroll
                for (int j = 0; j < 4; ++j) acc[i][j] += av[i] * bv[j];
        }
        __syncthreads();
    }
#pragma unroll
    for (int i = 0; i < 4; ++i)
#pragma unroll
        for (int j = 0; j < 4; ++j)
            C[(size_t)(mb + ty * 4 + i) * OUT_F + nb + tx * 4 + j] = acc[i][j] + bias[nb + tx * 4 + j];
}

extern "C" void kernel_launch(void* const* d_in, const int* in_sizes, int n_in,
                              void* d_out, int out_size, void* d_ws, size_t ws_size,
                              hipStream_t stream) {
    const float* x    = (const float*)d_in[0];
    const float* w1   = (const float*)d_in[1];
    const float* w2   = (const float*)d_in[2];
    const float* bias = (const float*)d_in[3];
    float* out = (float*)d_out;

    const size_t need = (size_t)TOKENS * IN_F + (size_t)OUT_F * IN_F;   // i8 bytes
    bool ok = false;
    if (ws_size >= need) {
        signed char* xb = (signed char*)d_ws;
        signed char* wb = xb + (size_t)TOKENS * IN_F;
        hipError_t e = hipFuncSetAttribute((const void*)k_gemmi8,
                                           hipFuncAttributeMaxDynamicSharedMemorySize, 131072);
        if (e == hipSuccess) {
            k_xquant<<<512, 256, 0, stream>>>((const float4*)x, (int4*)xb,
                                              TOKENS * IN_F / 16);
            k_ternarize<<<4096, 256, 0, stream>>>((const float4*)w1, (const float4*)w2,
                                                  (int4*)wb, OUT_F * IN_F / 16);
            k_gemmi8<<<dim3(1024), 256, 131072, stream>>>(xb, wb, bias, out);
            ok = true;
        }
    }
    if (!ok) {
        dim3 grid(OUT_F / 64, TOKENS / 64);
        k_fallback<<<grid, 256, 0, stream>>>(x, w1, w2, bias, out);
    }
}